// Round 14
// baseline (3119.834 us; speedup 1.0000x reference)
//
#include <hip/hip_runtime.h>

typedef __attribute__((ext_vector_type(4))) int   i32x4;
typedef __attribute__((ext_vector_type(4))) float f32x4;
typedef unsigned int u32;
typedef unsigned long long u64;
typedef unsigned char u8;
typedef unsigned short u16;

#define C_ 768
#define NPIX 256
#define ROWB 96            // bytes per padded pixel's bit-row (768 bits)
#define IMGBITS (324*ROWB) // 18x18 padded pixels x 96 B = 31104 B per image
// Aexp: [t 4][epr 4][lgrp 4][epc 18][16B] per buffer
#define GS   304
#define PRS  1232
#define TPL  4928          // 4*PRS per t-plane
#define AEXP2 19712        // 4 t-planes

#define WFRAG_SZ 10616832ull
// workspace map
#define OFF_WFRAG 0ull            // 3 x 10,616,832 (q,k,v i8 hi/lo frags)
#define OFF_WCOL  31850496ull     // 10,616,832 (i16 [tap][c][co] for sparse p)
#define OFF_BITS  42467328ull     // 5 x 1,990,656 (xs,q,k,v,o bit planes)
#define BITSZ     1990656ull
#define OFF_SBT   52420608ull     // 4 x 1536 f32
#define OFF_WMAX  52445184ull     // 4 f32

__device__ __forceinline__ i32x4 as_i4(uint4 v){ union{uint4 u; i32x4 s;} c; c.u=v; return c.s; }
#define SPREAD(NIB) ((u32)__mul24((int)(NIB), 0x204081) & 0x01010101u)

// ---------------- BN affine x4 ----------------
__global__ __launch_bounds__(256) void bn_prep4(
    const float* __restrict__ g0, const float* __restrict__ b0,
    const float* __restrict__ m0, const float* __restrict__ v0,
    const float* __restrict__ g1, const float* __restrict__ b1,
    const float* __restrict__ m1, const float* __restrict__ v1,
    const float* __restrict__ g2, const float* __restrict__ b2,
    const float* __restrict__ m2, const float* __restrict__ v2,
    const float* __restrict__ g3, const float* __restrict__ b3,
    const float* __restrict__ m3, const float* __restrict__ v3,
    float* __restrict__ out)
{
    int s = blockIdx.y;
    const float* g  = s==0?g0:s==1?g1:s==2?g2:g3;
    const float* be = s==0?b0:s==1?b1:s==2?b2:b3;
    const float* m  = s==0?m0:s==1?m1:s==2?m2:m3;
    const float* va = s==0?v0:s==1?v1:s==2?v2:v3;
    int i = blockIdx.x*256 + threadIdx.x;
    if (i < C_){
        float sc = g[i] / sqrtf(va[i] + 1e-5f);
        out[s*1536 + i] = sc;
        out[s*1536 + C_ + i] = be[i] - m[i]*sc;
    }
}

// ---------------- max|w| x4 ----------------
__global__ __launch_bounds__(256) void wmax4(
    const float* __restrict__ w0, const float* __restrict__ w1,
    const float* __restrict__ w2, const float* __restrict__ w3,
    float* __restrict__ out)
{
    int s = blockIdx.y;
    const float* w = s==0?w0:s==1?w1:s==2?w2:w3;
    const int n4 = 9*C_*C_/4;
    float m = 0.f;
    for (int i = blockIdx.x*256 + threadIdx.x; i < n4; i += 65536){
        f32x4 v = *(const f32x4*)(w + (size_t)i*4);
        m = fmaxf(m, fmaxf(fmaxf(fabsf(v[0]), fabsf(v[1])),
                           fmaxf(fabsf(v[2]), fabsf(v[3]))));
    }
    #pragma unroll
    for (int off = 32; off >= 1; off >>= 1)
        m = fmaxf(m, __shfl_xor(m, off));
    if ((threadIdx.x & 63) == 0)
        atomicMax((int*)(out + s), __float_as_int(m));
}

// ---- weight prep, LDS-staged coalesced (round-9 verified) ------------------
__global__ __launch_bounds__(256) void wprep_stage(
    const float* __restrict__ w0, const float* __restrict__ w1,
    const float* __restrict__ w2, const float* __restrict__ w3,
    const float* __restrict__ wmaxb, u8* __restrict__ wfbase,
    short* __restrict__ wcol)
{
    __shared__ float lds[16][580];
    const int tid = threadIdx.x;
    const int nfg = blockIdx.x, cch = blockIdx.y, s = blockIdx.z;
    const float* w = s==0?w0:s==1?w1:s==2?w2:w3;
    const float mw = wmaxb[s];
    const float invS = (mw > 0.f) ? (32512.0f / mw) : 0.f;

    #pragma unroll 1
    for (int i = tid; i < 16*144; i += 256){
        int r = i / 144, f4 = i - r*144;
        f32x4 v = *(const f32x4*)(w + (size_t)(nfg*16 + r)*6912 + cch*576 + f4*4);
        *(f32x4*)&lds[r][f4*4] = v;
    }
    __syncthreads();

    if (s < 3){
        u8* wf = wfbase + (size_t)s*WFRAG_SZ;
        #pragma unroll 1
        for (int rep = 0; rep < 3; ++rep){
            int idx = rep*256 + tid;
            if (idx < 576){
                int tap = idx >> 6, lane = idx & 63;
                int co_r = lane & 15, cg = lane >> 4;
                u32 hw[4] = {0,0,0,0}, lw[4] = {0,0,0,0};
                #pragma unroll
                for (int e=0;e<16;++e){
                    float f = lds[co_r][(cg*16 + e)*9 + tap];
                    int w16 = __float2int_rn(f * invS);
                    w16 = min(max(w16, -32512), 32512);
                    int hi = (w16 + 128) >> 8;
                    int lo = w16 - (hi << 8);
                    hw[e>>2] |= ((u32)(hi & 0xFF)) << ((e&3)*8);
                    lw[e>>2] |= ((u32)(lo & 0xFF)) << ((e&3)*8);
                }
                u8* base = wf + (((size_t)(cch*9 + tap)*48 + nfg)*2)*1024 + (size_t)lane*16;
                *(uint4*)(base)        = make_uint4(hw[0],hw[1],hw[2],hw[3]);
                *(uint4*)(base + 1024) = make_uint4(lw[0],lw[1],lw[2],lw[3]);
            }
        }
    } else {
        #pragma unroll 1
        for (int rep = 0; rep < 3; ++rep){
            int idx = rep*256 + tid;
            if (idx < 576){
                int tap = idx >> 6, cl = idx & 63;
                short ov[16];
                #pragma unroll
                for (int r=0;r<16;++r){
                    float f = lds[r][cl*9 + tap];
                    int w16 = __float2int_rn(f * invS);
                    w16 = min(max(w16, -32512), 32512);
                    ov[r] = (short)w16;
                }
                short* dst = wcol + ((size_t)tap*C_ + cch*64 + cl)*C_ + nfg*16;
                *(uint4*)(dst)     = *(uint4*)(&ov[0]);
                *(uint4*)(dst + 8) = *(uint4*)(&ov[8]);
            }
        }
    }
}

// ------- head LIF: x f32 [img][c][pix] -> padded bit rows ----
__global__ __launch_bounds__(256) void head_bits(
    const float* __restrict__ x, u8* __restrict__ bits)
{
    int gid = blockIdx.x*256 + threadIdx.x;
    int b = gid / 24576, rem = gid - b*24576;
    int cb = rem >> 8, pix = rem & 255;
    int pr = ((pix>>4)+1)*18 + (pix&15) + 1;
    float v[8];
    #pragma unroll
    for (int j=0;j<8;++j) v[j]=0.f;
    #pragma unroll
    for (int t=0;t<4;++t){
        int img = t*16 + b;
        u32 byte = 0;
        #pragma unroll
        for (int j=0;j<8;++j){
            float xv = x[((size_t)img*C_ + cb*8 + j)*NPIX + pix];
            float h = __fadd_rn(v[j], __fmul_rn(__fsub_rn(xv, v[j]), 0.5f));
            u32 s = (h >= 1.0f) ? 1u : 0u;
            v[j] = s ? 0.f : h;
            byte |= s << j;
        }
        bits[(size_t)img*IMGBITS + (size_t)pr*ROWB + cb] = (u8)byte;
    }
}

// ---- implicit-GEMM conv3x3 + BN + LIF + bit-pack, i8 hi/lo MFMA ------------
// Grid (1024, 3 s): cox=bid&7, mseg=(bid>>3)&7, bq=bid>>6; s selects q/k/v.
// 3 blocks/CU (12 waves): cross-block MFMA overlap during barrier drains.
// EXPW mid-BODY so its ds_writes clear before the barrier.
__global__ __launch_bounds__(256,3) void conv_lif(
    const u8* __restrict__ abits, const u8* __restrict__ wfbase,
    const float* __restrict__ sbt, const float* __restrict__ wmaxb,
    u8* __restrict__ obase)
{
    __shared__ __align__(16) u8 Aexp[2*AEXP2];
    const int tid = threadIdx.x;
    const int bid = blockIdx.x;
    const int s_idx = blockIdx.y;
    const u8* wf = wfbase + (size_t)s_idx*WFRAG_SZ;
    const float* sb = sbt + s_idx*1536;
    u8* obits = obase + (size_t)s_idx*BITSZ;
    const int cox = bid & 7, mseg = (bid >> 3) & 7, bq = bid >> 6;
    const int lane = tid & 63, w = tid >> 6;
    const int wr = w >> 1, wc = w & 1;
    const int lrow = lane & 15, lgrp = lane >> 4;

    const int t0u = tid / 72, p0 = tid - t0u*72;
    const int epr0 = p0 / 18, epc0 = p0 - epr0*18;
    const u8* b0 = abits + (size_t)(t0u*16 + bq)*IMGBITS
                 + (size_t)((mseg*2 + epr0)*18 + epc0)*ROWB;
    const int d0off = t0u*TPL + epr0*PRS + epc0*16;
    const bool has2 = (tid < 32);
    const int p1 = tid + 40;                       // unit 256..287 -> t=3
    const int epr1 = p1 / 18, epc1 = p1 - epr1*18;
    const u8* b1 = abits + (size_t)(3*16 + bq)*IMGBITS
                 + (size_t)((mseg*2 + epr1)*18 + epc1)*ROWB;
    const int d1off = 3*TPL + epr1*PRS + epc1*16;

#define EXPW(BW, DP){ \
    u32 lo_ = (u32)(BW), hi_ = (u32)((BW)>>32); \
    *(uint4*)((DP)       ) = make_uint4(SPREAD(lo_&0xF), SPREAD((lo_>>4)&0xF), SPREAD((lo_>>8)&0xF), SPREAD((lo_>>12)&0xF)); \
    *(uint4*)((DP) + GS  ) = make_uint4(SPREAD((lo_>>16)&0xF), SPREAD((lo_>>20)&0xF), SPREAD((lo_>>24)&0xF), SPREAD((lo_>>28)&0xF)); \
    *(uint4*)((DP) + 2*GS) = make_uint4(SPREAD(hi_&0xF), SPREAD((hi_>>4)&0xF), SPREAD((hi_>>8)&0xF), SPREAD((hi_>>12)&0xF)); \
    *(uint4*)((DP) + 3*GS) = make_uint4(SPREAD((hi_>>16)&0xF), SPREAD((hi_>>20)&0xF), SPREAD((hi_>>24)&0xF), SPREAD((hi_>>28)&0xF)); }

    const u8* wp = wf + (size_t)((cox*6 + wc*3)*2)*1024 + (size_t)lane*16;
    uint4 R0[6], R1[6], R2[6];
#define LOADB(BUF) { \
    _Pragma("unroll") \
    for (int j=0;j<6;++j) BUF[j] = *(const uint4*)(wp + (j>>1)*2048 + (j&1)*1024); \
    wp += 98304; }

    const int rb = (wr + 1)*PRS + lgrp*GS + (lrow + 1)*16;

    i32x4 acc_h[4][3], acc_l[4][3];
    #pragma unroll
    for (int t=0;t<4;++t)
        #pragma unroll
        for (int ni=0;ni<3;++ni)
            #pragma unroll
            for (int r=0;r<4;++r){ acc_h[t][ni][r]=0; acc_l[t][ni][r]=0; }

#define COMPUTE(BUF, AE, TAP) { \
    const int DT = ((TAP)/3 - 1)*PRS + (((TAP)%3) - 1)*16; \
    i32x4 af[4]; \
    _Pragma("unroll") \
    for (int t=0;t<4;++t) af[t] = *(const i32x4*)((AE) + t*TPL + rb + DT); \
    __builtin_amdgcn_s_setprio(1); \
    _Pragma("unroll") \
    for (int t=0;t<4;++t){ \
        _Pragma("unroll") \
        for (int ni=0;ni<3;++ni){ \
            acc_h[t][ni] = __builtin_amdgcn_mfma_i32_16x16x64_i8(af[t], as_i4(BUF[ni*2+0]), acc_h[t][ni], 0,0,0); \
            acc_l[t][ni] = __builtin_amdgcn_mfma_i32_16x16x64_i8(af[t], as_i4(BUF[ni*2+1]), acc_l[t][ni], 0,0,0); \
        } \
    } \
    __builtin_amdgcn_s_setprio(0); }

#define BODY(CCH, BOFF) { \
    u64 bw0n = 0, bw1n = 0; \
    if ((CCH) < 11){ \
        bw0n = *(const u64*)(b0 + ((CCH)+1)*8); \
        if (has2) bw1n = *(const u64*)(b1 + ((CCH)+1)*8); \
    } \
    const u8* Ae = Aexp + (BOFF); \
    LOADB(R2); COMPUTE(R0, Ae, 0); \
    LOADB(R0); COMPUTE(R1, Ae, 1); \
    LOADB(R1); COMPUTE(R2, Ae, 2); \
    LOADB(R2); COMPUTE(R0, Ae, 3); \
    LOADB(R0); COMPUTE(R1, Ae, 4); \
    if ((CCH) < 11){ \
        EXPW(bw0n, Aexp + ((BOFF) ^ AEXP2) + d0off); \
        if (has2) EXPW(bw1n, Aexp + ((BOFF) ^ AEXP2) + d1off); \
    } \
    LOADB(R1); COMPUTE(R2, Ae, 5); \
    LOADB(R2); COMPUTE(R0, Ae, 6); \
    LOADB(R0); COMPUTE(R1, Ae, 7); \
    LOADB(R1); COMPUTE(R2, Ae, 8); \
    __syncthreads(); }

    LOADB(R0); LOADB(R1);
    {
        u64 bw0 = *(const u64*)(b0);
        EXPW(bw0, Aexp + d0off);
        if (has2){
            u64 bw1 = *(const u64*)(b1);
            EXPW(bw1, Aexp + d1off);
        }
    }
    __syncthreads();

    #pragma unroll 1
    for (int c2=0; c2<6; ++c2){
        BODY(2*c2,   0);
        BODY(2*c2+1, AEXP2);
    }
#undef LOADB
#undef EXPW
#undef COMPUTE
#undef BODY

    // epilogue: exact BN + LIF over t (regs) + ballot bit-pack -> bit plane
    const float S = wmaxb[s_idx] * (1.0f/32512.0f);
    float scs[3], bis[3];
    #pragma unroll
    for (int ni=0;ni<3;++ni){
        const int co = cox*96 + wc*48 + ni*16 + lrow;
        scs[ni] = sb[co]; bis[ni] = sb[C_ + co];
    }
    float vmem[3][4];
    #pragma unroll
    for (int ni=0;ni<3;++ni)
        #pragma unroll
        for (int r=0;r<4;++r) vmem[ni][r] = 0.f;

    const int pixb = mseg*32 + wr*16 + lgrp*4;
    const int prn0 = ((pixb>>4)+1)*18 + (pixb&15) + 1;
    #pragma unroll
    for (int t=0;t<4;++t){
        const size_t ibase = (size_t)(t*16 + bq)*IMGBITS;
        #pragma unroll
        for (int ni=0;ni<3;++ni){
            #pragma unroll
            for (int r=0;r<4;++r){
                int sum = acc_h[t][ni][r]*256 + acc_l[t][ni][r];
                float accf = (float)sum * S;
                float y = __fadd_rn(__fmul_rn(accf, scs[ni]), bis[ni]);
                float h = __fadd_rn(vmem[ni][r],
                          __fmul_rn(__fsub_rn(y, vmem[ni][r]), 0.5f));
                u32 s = (h >= 1.0f) ? 1u : 0u;
                vmem[ni][r] = s ? 0.f : h;
                u64 mask = __ballot((int)s);
                if (lrow == 0){
                    u16 fld = (u16)(mask >> (lgrp*16));
                    *(u16*)(obits + ibase + (size_t)(prn0 + r)*ROWB
                            + cox*12 + wc*6 + ni*2) = fld;
                }
            }
        }
    }
}

// ---------------- attention: bit-plane in/out (round-9 verified) ------------
__global__ __launch_bounds__(512) void attn_bits(
    const u8* __restrict__ qb_, const u8* __restrict__ kb_,
    const u8* __restrict__ vb_, u8* __restrict__ ob)
{
    const int tid = threadIdx.x;
    const int b = blockIdx.x, h = blockIdx.y;
    __shared__ u64 kb[96][4], vb[96][4];
    __shared__ float kvl[96][96];
    const int w = tid >> 6, lane = tid & 63;
    const int ng = w & 3, n_build = ng*64 + lane;
    const int n = tid & 255, eh = tid >> 8;
    const int prb = ((n_build>>4)+1)*18 + (n_build&15) + 1;
    const int prn = ((n>>4)+1)*18 + (n&15) + 1;
    float vmem[48];
    #pragma unroll
    for (int e=0;e<48;++e) vmem[e]=0.f;

    for (int t=0;t<4;++t){
        const int img = t*16 + b;
        {
            const u8* src = (w < 4 ? kb_ : vb_) + (size_t)img*IMGBITS
                          + (size_t)prb*ROWB + h*12;
            u32 kw0 = ((const u32*)src)[0];
            u32 kw1 = ((const u32*)src)[1];
            u32 kw2 = ((const u32*)src)[2];
            u64 (*dst)[4] = (w < 4) ? kb : vb;
            #pragma unroll 1
            for (int dj=0; dj<32; ++dj){
                u64 m = __ballot((int)((kw0 >> dj) & 1u));
                if (lane == 0) dst[dj][ng] = m;
            }
            #pragma unroll 1
            for (int dj=0; dj<32; ++dj){
                u64 m = __ballot((int)((kw1 >> dj) & 1u));
                if (lane == 0) dst[32+dj][ng] = m;
            }
            #pragma unroll 1
            for (int dj=0; dj<32; ++dj){
                u64 m = __ballot((int)((kw2 >> dj) & 1u));
                if (lane == 0) dst[64+dj][ng] = m;
            }
        }
        __syncthreads();
        for (int i = tid; i < 96*96; i += 512){
            int d = i / 96, e = i - d*96;
            int s = 0;
            #pragma unroll
            for (int g=0; g<4; ++g) s += __popcll(kb[d][g] & vb[e][g]);
            kvl[d][e] = (float)s;
        }
        __syncthreads();
        {
            const u8* qsrc = qb_ + (size_t)img*IMGBITS + (size_t)prn*ROWB + h*12;
            u32 qw0 = ((const u32*)qsrc)[0];
            u32 qw1 = ((const u32*)qsrc)[1];
            u32 qw2 = ((const u32*)qsrc)[2];
            float val[48];
            #pragma unroll
            for (int e=0;e<48;++e) val[e]=0.f;
            #pragma unroll 1
            for (int d=0; d<96; ++d){
                u32 ww = (d < 32) ? qw0 : (d < 64) ? qw1 : qw2;
                u32 qv = (ww >> (d & 31)) & 1u;
                if (__any((int)qv)){
                    float qf = (float)qv;
                    #pragma unroll
                    for (int e=0;e<48;++e) val[e] += qf * kvl[d][eh*48+e];
                }
            }
            u64 wbits = 0;
            #pragma unroll
            for (int e=0;e<48;++e){
                float o = val[e]*0.125f;
                float hh = __fadd_rn(vmem[e], __fmul_rn(__fsub_rn(o, vmem[e]), 0.5f));
                u32 s = (hh >= 0.5f) ? 1u : 0u;
                vmem[e] = s ? 0.f : hh;
                wbits |= (u64)s << e;
            }
            u8* od = ob + (size_t)img*IMGBITS + (size_t)prn*ROWB + h*12 + eh*6;
            *(u16*)(od)     = (u16)(wbits);
            *(u16*)(od + 2) = (u16)(wbits >> 16);
            *(u16*)(od + 4) = (u16)(wbits >> 32);
        }
        __syncthreads();
    }
}

// ---------------- sparse exact p-conv + BN (verified) -----------------------
__global__ __launch_bounds__(256) void pconv_sparse(
    const u8* __restrict__ ob, const short* __restrict__ wcol,
    const float* __restrict__ sb, const float* __restrict__ wmaxp,
    float* __restrict__ out)
{
    __shared__ u64 bl[648];
    __shared__ int accL[16*768];
    const int tid = threadIdx.x;
    const int img = blockIdx.x >> 4, y = blockIdx.x & 15;

    for (int idx = tid; idx < 648; idx += 256){
        int d = idx / 216, wi = idx - d*216;
        bl[idx] = *(const u64*)(ob + (size_t)img*IMGBITS
                                + (size_t)((y+d)*18)*ROWB + (size_t)wi*8);
    }
    for (int idx = tid; idx < 16*768; idx += 256) accL[idx] = 0;
    __syncthreads();

    #pragma unroll 1
    for (int wi = 0; wi < 648; ++wi){
        u64 v = bl[wi];
        if (!v) continue;
        while (v){
            int j = __ffsll((unsigned long long)v) - 1;
            v &= v - 1;
            int byt = wi*8 + (j >> 3);
            int p = byt / 96;
            int c = (byt - p*96)*8 + (j & 7);
            int dd = p / 18, px = p - dd*18;
            #pragma unroll
            for (int xi = 0; xi < 3; ++xi){
                int x = px - 2 + xi;
                if ((unsigned)x < 16u){
                    int tap = dd*3 + 2 - xi;
                    const short* wr_ = wcol + ((size_t)tap*C_ + c)*C_;
                    #pragma unroll
                    for (int q = 0; q < 3; ++q){
                        int co = tid + q*256;
                        accL[x*768 + co] += (int)wr_[co];
                    }
                }
            }
        }
    }
    __syncthreads();

    const float S = wmaxp[0] * (1.0f/32512.0f);
    #pragma unroll
    for (int q = 0; q < 3; ++q){
        int co = tid + q*256;
        float sc = sb[co], bi = sb[C_ + co];
        float* op = out + ((size_t)img*C_ + co)*NPIX + y*16;
        #pragma unroll
        for (int xg = 0; xg < 4; ++xg){
            f32x4 o4;
            #pragma unroll
            for (int rr = 0; rr < 4; ++rr){
                float accf = (float)accL[(xg*4+rr)*768 + co] * S;
                o4[rr] = __fadd_rn(__fmul_rn(accf, sc), bi);
            }
            *(f32x4*)(op + xg*4) = o4;
        }
    }
}

// ---------------------------------------------------------------------------
extern "C" void kernel_launch(void* const* d_in, const int* in_sizes, int n_in,
                              void* d_out, int out_size, void* d_ws, size_t ws_size,
                              hipStream_t stream)
{
    u8* ws = (u8*)d_ws;
    u8* wfrag = ws + OFF_WFRAG;
    short* wcol = (short*)(ws + OFF_WCOL);
    u8* xs_b = ws + OFF_BITS;
    u8* q_b  = ws + OFF_BITS + 1*BITSZ;
    u8* o_b  = ws + OFF_BITS + 4*BITSZ;
    float* sbt = (float*)(ws + OFF_SBT);
    float* wmaxb = (float*)(ws + OFF_WMAX);
    float* outp = (float*)d_out;

    hipMemsetAsync(ws + OFF_BITS, 0, 5*BITSZ, stream);   // bit halos must be 0
    hipMemsetAsync(wmaxb, 0, 16, stream);

    bn_prep4<<<dim3(3,4),256,0,stream>>>(
        (const float*)d_in[2],  (const float*)d_in[3],  (const float*)d_in[4],  (const float*)d_in[5],
        (const float*)d_in[7],  (const float*)d_in[8],  (const float*)d_in[9],  (const float*)d_in[10],
        (const float*)d_in[12], (const float*)d_in[13], (const float*)d_in[14], (const float*)d_in[15],
        (const float*)d_in[17], (const float*)d_in[18], (const float*)d_in[19], (const float*)d_in[20],
        sbt);
    wmax4<<<dim3(256,4),256,0,stream>>>(
        (const float*)d_in[1], (const float*)d_in[6],
        (const float*)d_in[11], (const float*)d_in[16], wmaxb);
    wprep_stage<<<dim3(48,12,4),256,0,stream>>>(
        (const float*)d_in[1], (const float*)d_in[6],
        (const float*)d_in[11], (const float*)d_in[16], wmaxb, wfrag, wcol);
    head_bits<<<1536,256,0,stream>>>((const float*)d_in[0], xs_b);

    conv_lif<<<dim3(1024,3),256,0,stream>>>(xs_b, wfrag, sbt, wmaxb, q_b);

    attn_bits<<<dim3(16,8),512,0,stream>>>(q_b, q_b + BITSZ, q_b + 2*BITSZ, o_b);
    pconv_sparse<<<1024,256,0,stream>>>(o_b, wcol, sbt + 4608, wmaxb + 3, outp);
}

// Round 15
// 573.694 us; speedup vs baseline: 5.4382x; 5.4382x over previous
//
#include <hip/hip_runtime.h>

typedef __attribute__((ext_vector_type(4))) int   i32x4;
typedef __attribute__((ext_vector_type(4))) float f32x4;
typedef unsigned int u32;
typedef unsigned long long u64;
typedef unsigned char u8;
typedef unsigned short u16;

#define C_ 768
#define NPIX 256
#define ROWB 96            // bytes per padded pixel's bit-row (768 bits)
#define IMGBITS (324*ROWB) // 18x18 padded pixels x 96 B = 31104 B per image
// Aexp: [t 4][epr 4][lgrp 4][epc 18][16B] per buffer
#define GS   304
#define PRS  1232
#define TPL  4928          // 4*PRS per t-plane
#define AEXP2 19712        // 4 t-planes

#define WFRAG_SZ 10616832ull
// workspace map
#define OFF_WFRAG 0ull            // 3 x 10,616,832 (q,k,v i8 hi/lo frags)
#define OFF_WCOL  31850496ull     // 10,616,832 (i16 [tap][c][co] for sparse p)
#define OFF_BITS  42467328ull     // 5 x 1,990,656 (xs,q,k,v,o bit planes)
#define BITSZ     1990656ull
#define OFF_SBT   52420608ull     // 4 x 1536 f32
#define OFF_WMAX  52445184ull     // 4 f32

__device__ __forceinline__ i32x4 as_i4(uint4 v){ union{uint4 u; i32x4 s;} c; c.u=v; return c.s; }
#define SPREAD(NIB) ((u32)__mul24((int)(NIB), 0x204081) & 0x01010101u)

// ---------------- BN affine x4 ----------------
__global__ __launch_bounds__(256) void bn_prep4(
    const float* __restrict__ g0, const float* __restrict__ b0,
    const float* __restrict__ m0, const float* __restrict__ v0,
    const float* __restrict__ g1, const float* __restrict__ b1,
    const float* __restrict__ m1, const float* __restrict__ v1,
    const float* __restrict__ g2, const float* __restrict__ b2,
    const float* __restrict__ m2, const float* __restrict__ v2,
    const float* __restrict__ g3, const float* __restrict__ b3,
    const float* __restrict__ m3, const float* __restrict__ v3,
    float* __restrict__ out)
{
    int s = blockIdx.y;
    const float* g  = s==0?g0:s==1?g1:s==2?g2:g3;
    const float* be = s==0?b0:s==1?b1:s==2?b2:b3;
    const float* m  = s==0?m0:s==1?m1:s==2?m2:m3;
    const float* va = s==0?v0:s==1?v1:s==2?v2:v3;
    int i = blockIdx.x*256 + threadIdx.x;
    if (i < C_){
        float sc = g[i] / sqrtf(va[i] + 1e-5f);
        out[s*1536 + i] = sc;
        out[s*1536 + C_ + i] = be[i] - m[i]*sc;
    }
}

// ---------------- max|w| x4 ----------------
__global__ __launch_bounds__(256) void wmax4(
    const float* __restrict__ w0, const float* __restrict__ w1,
    const float* __restrict__ w2, const float* __restrict__ w3,
    float* __restrict__ out)
{
    int s = blockIdx.y;
    const float* w = s==0?w0:s==1?w1:s==2?w2:w3;
    const int n4 = 9*C_*C_/4;
    float m = 0.f;
    for (int i = blockIdx.x*256 + threadIdx.x; i < n4; i += 65536){
        f32x4 v = *(const f32x4*)(w + (size_t)i*4);
        m = fmaxf(m, fmaxf(fmaxf(fabsf(v[0]), fabsf(v[1])),
                           fmaxf(fabsf(v[2]), fabsf(v[3]))));
    }
    #pragma unroll
    for (int off = 32; off >= 1; off >>= 1)
        m = fmaxf(m, __shfl_xor(m, off));
    if ((threadIdx.x & 63) == 0)
        atomicMax((int*)(out + s), __float_as_int(m));
}

// ---- weight prep, LDS-staged coalesced (round-9 verified) ------------------
__global__ __launch_bounds__(256) void wprep_stage(
    const float* __restrict__ w0, const float* __restrict__ w1,
    const float* __restrict__ w2, const float* __restrict__ w3,
    const float* __restrict__ wmaxb, u8* __restrict__ wfbase,
    short* __restrict__ wcol)
{
    __shared__ float lds[16][580];
    const int tid = threadIdx.x;
    const int nfg = blockIdx.x, cch = blockIdx.y, s = blockIdx.z;
    const float* w = s==0?w0:s==1?w1:s==2?w2:w3;
    const float mw = wmaxb[s];
    const float invS = (mw > 0.f) ? (32512.0f / mw) : 0.f;

    #pragma unroll 1
    for (int i = tid; i < 16*144; i += 256){
        int r = i / 144, f4 = i - r*144;
        f32x4 v = *(const f32x4*)(w + (size_t)(nfg*16 + r)*6912 + cch*576 + f4*4);
        *(f32x4*)&lds[r][f4*4] = v;
    }
    __syncthreads();

    if (s < 3){
        u8* wf = wfbase + (size_t)s*WFRAG_SZ;
        #pragma unroll 1
        for (int rep = 0; rep < 3; ++rep){
            int idx = rep*256 + tid;
            if (idx < 576){
                int tap = idx >> 6, lane = idx & 63;
                int co_r = lane & 15, cg = lane >> 4;
                u32 hw[4] = {0,0,0,0}, lw[4] = {0,0,0,0};
                #pragma unroll
                for (int e=0;e<16;++e){
                    float f = lds[co_r][(cg*16 + e)*9 + tap];
                    int w16 = __float2int_rn(f * invS);
                    w16 = min(max(w16, -32512), 32512);
                    int hi = (w16 + 128) >> 8;
                    int lo = w16 - (hi << 8);
                    hw[e>>2] |= ((u32)(hi & 0xFF)) << ((e&3)*8);
                    lw[e>>2] |= ((u32)(lo & 0xFF)) << ((e&3)*8);
                }
                u8* base = wf + (((size_t)(cch*9 + tap)*48 + nfg)*2)*1024 + (size_t)lane*16;
                *(uint4*)(base)        = make_uint4(hw[0],hw[1],hw[2],hw[3]);
                *(uint4*)(base + 1024) = make_uint4(lw[0],lw[1],lw[2],lw[3]);
            }
        }
    } else {
        #pragma unroll 1
        for (int rep = 0; rep < 3; ++rep){
            int idx = rep*256 + tid;
            if (idx < 576){
                int tap = idx >> 6, cl = idx & 63;
                short ov[16];
                #pragma unroll
                for (int r=0;r<16;++r){
                    float f = lds[r][cl*9 + tap];
                    int w16 = __float2int_rn(f * invS);
                    w16 = min(max(w16, -32512), 32512);
                    ov[r] = (short)w16;
                }
                short* dst = wcol + ((size_t)tap*C_ + cch*64 + cl)*C_ + nfg*16;
                *(uint4*)(dst)     = *(uint4*)(&ov[0]);
                *(uint4*)(dst + 8) = *(uint4*)(&ov[8]);
            }
        }
    }
}

// ------- head LIF: x f32 [img][c][pix] -> padded bit rows ----
__global__ __launch_bounds__(256) void head_bits(
    const float* __restrict__ x, u8* __restrict__ bits)
{
    int gid = blockIdx.x*256 + threadIdx.x;
    int b = gid / 24576, rem = gid - b*24576;
    int cb = rem >> 8, pix = rem & 255;
    int pr = ((pix>>4)+1)*18 + (pix&15) + 1;
    float v[8];
    #pragma unroll
    for (int j=0;j<8;++j) v[j]=0.f;
    #pragma unroll
    for (int t=0;t<4;++t){
        int img = t*16 + b;
        u32 byte = 0;
        #pragma unroll
        for (int j=0;j<8;++j){
            float xv = x[((size_t)img*C_ + cb*8 + j)*NPIX + pix];
            float h = __fadd_rn(v[j], __fmul_rn(__fsub_rn(xv, v[j]), 0.5f));
            u32 s = (h >= 1.0f) ? 1u : 0u;
            v[j] = s ? 0.f : h;
            byte |= s << j;
        }
        bits[(size_t)img*IMGBITS + (size_t)pr*ROWB + cb] = (u8)byte;
    }
}

// ---- implicit-GEMM conv3x3 + BN + LIF + bit-pack, i8 hi/lo MFMA ------------
// Grid (1024, 3 s): cox=bid&7, mseg=(bid>>3)&7, bq=bid>>6; s selects q/k/v.
// __launch_bounds__(256,2): the verified register regime (VGPR=128; asking
// for 3 blocks/CU in round 14 spilled the B-ring to scratch -> 5 GB/dispatch).
__global__ __launch_bounds__(256,2) void conv_lif(
    const u8* __restrict__ abits, const u8* __restrict__ wfbase,
    const float* __restrict__ sbt, const float* __restrict__ wmaxb,
    u8* __restrict__ obase)
{
    __shared__ __align__(16) u8 Aexp[2*AEXP2];
    const int tid = threadIdx.x;
    const int bid = blockIdx.x;
    const int s_idx = blockIdx.y;
    const u8* wf = wfbase + (size_t)s_idx*WFRAG_SZ;
    const float* sb = sbt + s_idx*1536;
    u8* obits = obase + (size_t)s_idx*BITSZ;
    const int cox = bid & 7, mseg = (bid >> 3) & 7, bq = bid >> 6;
    const int lane = tid & 63, w = tid >> 6;
    const int wr = w >> 1, wc = w & 1;
    const int lrow = lane & 15, lgrp = lane >> 4;

    const int t0u = tid / 72, p0 = tid - t0u*72;
    const int epr0 = p0 / 18, epc0 = p0 - epr0*18;
    const u8* b0 = abits + (size_t)(t0u*16 + bq)*IMGBITS
                 + (size_t)((mseg*2 + epr0)*18 + epc0)*ROWB;
    const int d0off = t0u*TPL + epr0*PRS + epc0*16;
    const bool has2 = (tid < 32);
    const int p1 = tid + 40;                       // unit 256..287 -> t=3
    const int epr1 = p1 / 18, epc1 = p1 - epr1*18;
    const u8* b1 = abits + (size_t)(3*16 + bq)*IMGBITS
                 + (size_t)((mseg*2 + epr1)*18 + epc1)*ROWB;
    const int d1off = 3*TPL + epr1*PRS + epc1*16;

#define EXPW(BW, DP){ \
    u32 lo_ = (u32)(BW), hi_ = (u32)((BW)>>32); \
    *(uint4*)((DP)       ) = make_uint4(SPREAD(lo_&0xF), SPREAD((lo_>>4)&0xF), SPREAD((lo_>>8)&0xF), SPREAD((lo_>>12)&0xF)); \
    *(uint4*)((DP) + GS  ) = make_uint4(SPREAD((lo_>>16)&0xF), SPREAD((lo_>>20)&0xF), SPREAD((lo_>>24)&0xF), SPREAD((lo_>>28)&0xF)); \
    *(uint4*)((DP) + 2*GS) = make_uint4(SPREAD(hi_&0xF), SPREAD((hi_>>4)&0xF), SPREAD((hi_>>8)&0xF), SPREAD((hi_>>12)&0xF)); \
    *(uint4*)((DP) + 3*GS) = make_uint4(SPREAD((hi_>>16)&0xF), SPREAD((hi_>>20)&0xF), SPREAD((hi_>>24)&0xF), SPREAD((hi_>>28)&0xF)); }

    const u8* wp = wf + (size_t)((cox*6 + wc*3)*2)*1024 + (size_t)lane*16;
    uint4 R0[6], R1[6], R2[6];
#define LOADB(BUF) { \
    _Pragma("unroll") \
    for (int j=0;j<6;++j) BUF[j] = *(const uint4*)(wp + (j>>1)*2048 + (j&1)*1024); \
    wp += 98304; }

    const int rb = (wr + 1)*PRS + lgrp*GS + (lrow + 1)*16;

    i32x4 acc_h[4][3], acc_l[4][3];
    #pragma unroll
    for (int t=0;t<4;++t)
        #pragma unroll
        for (int ni=0;ni<3;++ni)
            #pragma unroll
            for (int r=0;r<4;++r){ acc_h[t][ni][r]=0; acc_l[t][ni][r]=0; }

#define COMPUTE(BUF, AE, TAP) { \
    const int DT = ((TAP)/3 - 1)*PRS + (((TAP)%3) - 1)*16; \
    i32x4 af[4]; \
    _Pragma("unroll") \
    for (int t=0;t<4;++t) af[t] = *(const i32x4*)((AE) + t*TPL + rb + DT); \
    __builtin_amdgcn_s_setprio(1); \
    _Pragma("unroll") \
    for (int t=0;t<4;++t){ \
        _Pragma("unroll") \
        for (int ni=0;ni<3;++ni){ \
            acc_h[t][ni] = __builtin_amdgcn_mfma_i32_16x16x64_i8(af[t], as_i4(BUF[ni*2+0]), acc_h[t][ni], 0,0,0); \
            acc_l[t][ni] = __builtin_amdgcn_mfma_i32_16x16x64_i8(af[t], as_i4(BUF[ni*2+1]), acc_l[t][ni], 0,0,0); \
        } \
    } \
    __builtin_amdgcn_s_setprio(0); }

#define BODY(CCH, BOFF) { \
    u64 bw0n = 0, bw1n = 0; \
    if ((CCH) < 11){ \
        bw0n = *(const u64*)(b0 + ((CCH)+1)*8); \
        if (has2) bw1n = *(const u64*)(b1 + ((CCH)+1)*8); \
    } \
    const u8* Ae = Aexp + (BOFF); \
    LOADB(R2); COMPUTE(R0, Ae, 0); \
    LOADB(R0); COMPUTE(R1, Ae, 1); \
    LOADB(R1); COMPUTE(R2, Ae, 2); \
    LOADB(R2); COMPUTE(R0, Ae, 3); \
    LOADB(R0); COMPUTE(R1, Ae, 4); \
    if ((CCH) < 11){ \
        EXPW(bw0n, Aexp + ((BOFF) ^ AEXP2) + d0off); \
        if (has2) EXPW(bw1n, Aexp + ((BOFF) ^ AEXP2) + d1off); \
    } \
    LOADB(R1); COMPUTE(R2, Ae, 5); \
    LOADB(R2); COMPUTE(R0, Ae, 6); \
    LOADB(R0); COMPUTE(R1, Ae, 7); \
    LOADB(R1); COMPUTE(R2, Ae, 8); \
    __syncthreads(); }

    LOADB(R0); LOADB(R1);
    {
        u64 bw0 = *(const u64*)(b0);
        EXPW(bw0, Aexp + d0off);
        if (has2){
            u64 bw1 = *(const u64*)(b1);
            EXPW(bw1, Aexp + d1off);
        }
    }
    __syncthreads();

    #pragma unroll 1
    for (int c2=0; c2<6; ++c2){
        BODY(2*c2,   0);
        BODY(2*c2+1, AEXP2);
    }
#undef LOADB
#undef EXPW
#undef COMPUTE
#undef BODY

    // epilogue: exact BN + LIF over t (regs) + ballot bit-pack -> bit plane
    const float S = wmaxb[s_idx] * (1.0f/32512.0f);
    float scs[3], bis[3];
    #pragma unroll
    for (int ni=0;ni<3;++ni){
        const int co = cox*96 + wc*48 + ni*16 + lrow;
        scs[ni] = sb[co]; bis[ni] = sb[C_ + co];
    }
    float vmem[3][4];
    #pragma unroll
    for (int ni=0;ni<3;++ni)
        #pragma unroll
        for (int r=0;r<4;++r) vmem[ni][r] = 0.f;

    const int pixb = mseg*32 + wr*16 + lgrp*4;
    const int prn0 = ((pixb>>4)+1)*18 + (pixb&15) + 1;
    #pragma unroll
    for (int t=0;t<4;++t){
        const size_t ibase = (size_t)(t*16 + bq)*IMGBITS;
        #pragma unroll
        for (int ni=0;ni<3;++ni){
            #pragma unroll
            for (int r=0;r<4;++r){
                int sum = acc_h[t][ni][r]*256 + acc_l[t][ni][r];
                float accf = (float)sum * S;
                float y = __fadd_rn(__fmul_rn(accf, scs[ni]), bis[ni]);
                float h = __fadd_rn(vmem[ni][r],
                          __fmul_rn(__fsub_rn(y, vmem[ni][r]), 0.5f));
                u32 s = (h >= 1.0f) ? 1u : 0u;
                vmem[ni][r] = s ? 0.f : h;
                u64 mask = __ballot((int)s);
                if (lrow == 0){
                    u16 fld = (u16)(mask >> (lgrp*16));
                    *(u16*)(obits + ibase + (size_t)(prn0 + r)*ROWB
                            + cox*12 + wc*6 + ni*2) = fld;
                }
            }
        }
    }
}

// ---------------- attention: bit-plane in/out (round-9 verified) ------------
__global__ __launch_bounds__(512) void attn_bits(
    const u8* __restrict__ qb_, const u8* __restrict__ kb_,
    const u8* __restrict__ vb_, u8* __restrict__ ob)
{
    const int tid = threadIdx.x;
    const int b = blockIdx.x, h = blockIdx.y;
    __shared__ u64 kb[96][4], vb[96][4];
    __shared__ float kvl[96][96];
    const int w = tid >> 6, lane = tid & 63;
    const int ng = w & 3, n_build = ng*64 + lane;
    const int n = tid & 255, eh = tid >> 8;
    const int prb = ((n_build>>4)+1)*18 + (n_build&15) + 1;
    const int prn = ((n>>4)+1)*18 + (n&15) + 1;
    float vmem[48];
    #pragma unroll
    for (int e=0;e<48;++e) vmem[e]=0.f;

    for (int t=0;t<4;++t){
        const int img = t*16 + b;
        {
            const u8* src = (w < 4 ? kb_ : vb_) + (size_t)img*IMGBITS
                          + (size_t)prb*ROWB + h*12;
            u32 kw0 = ((const u32*)src)[0];
            u32 kw1 = ((const u32*)src)[1];
            u32 kw2 = ((const u32*)src)[2];
            u64 (*dst)[4] = (w < 4) ? kb : vb;
            #pragma unroll 1
            for (int dj=0; dj<32; ++dj){
                u64 m = __ballot((int)((kw0 >> dj) & 1u));
                if (lane == 0) dst[dj][ng] = m;
            }
            #pragma unroll 1
            for (int dj=0; dj<32; ++dj){
                u64 m = __ballot((int)((kw1 >> dj) & 1u));
                if (lane == 0) dst[32+dj][ng] = m;
            }
            #pragma unroll 1
            for (int dj=0; dj<32; ++dj){
                u64 m = __ballot((int)((kw2 >> dj) & 1u));
                if (lane == 0) dst[64+dj][ng] = m;
            }
        }
        __syncthreads();
        for (int i = tid; i < 96*96; i += 512){
            int d = i / 96, e = i - d*96;
            int s = 0;
            #pragma unroll
            for (int g=0; g<4; ++g) s += __popcll(kb[d][g] & vb[e][g]);
            kvl[d][e] = (float)s;
        }
        __syncthreads();
        {
            const u8* qsrc = qb_ + (size_t)img*IMGBITS + (size_t)prn*ROWB + h*12;
            u32 qw0 = ((const u32*)qsrc)[0];
            u32 qw1 = ((const u32*)qsrc)[1];
            u32 qw2 = ((const u32*)qsrc)[2];
            float val[48];
            #pragma unroll
            for (int e=0;e<48;++e) val[e]=0.f;
            #pragma unroll 1
            for (int d=0; d<96; ++d){
                u32 ww = (d < 32) ? qw0 : (d < 64) ? qw1 : qw2;
                u32 qv = (ww >> (d & 31)) & 1u;
                if (__any((int)qv)){
                    float qf = (float)qv;
                    #pragma unroll
                    for (int e=0;e<48;++e) val[e] += qf * kvl[d][eh*48+e];
                }
            }
            u64 wbits = 0;
            #pragma unroll
            for (int e=0;e<48;++e){
                float o = val[e]*0.125f;
                float hh = __fadd_rn(vmem[e], __fmul_rn(__fsub_rn(o, vmem[e]), 0.5f));
                u32 s = (hh >= 0.5f) ? 1u : 0u;
                vmem[e] = s ? 0.f : hh;
                wbits |= (u64)s << e;
            }
            u8* od = ob + (size_t)img*IMGBITS + (size_t)prn*ROWB + h*12 + eh*6;
            *(u16*)(od)     = (u16)(wbits);
            *(u16*)(od + 2) = (u16)(wbits >> 16);
            *(u16*)(od + 4) = (u16)(wbits >> 32);
        }
        __syncthreads();
    }
}

// ---------------- sparse exact p-conv + BN (verified) -----------------------
__global__ __launch_bounds__(256) void pconv_sparse(
    const u8* __restrict__ ob, const short* __restrict__ wcol,
    const float* __restrict__ sb, const float* __restrict__ wmaxp,
    float* __restrict__ out)
{
    __shared__ u64 bl[648];
    __shared__ int accL[16*768];
    const int tid = threadIdx.x;
    const int img = blockIdx.x >> 4, y = blockIdx.x & 15;

    for (int idx = tid; idx < 648; idx += 256){
        int d = idx / 216, wi = idx - d*216;
        bl[idx] = *(const u64*)(ob + (size_t)img*IMGBITS
                                + (size_t)((y+d)*18)*ROWB + (size_t)wi*8);
    }
    for (int idx = tid; idx < 16*768; idx += 256) accL[idx] = 0;
    __syncthreads();

    #pragma unroll 1
    for (int wi = 0; wi < 648; ++wi){
        u64 v = bl[wi];
        if (!v) continue;
        while (v){
            int j = __ffsll((unsigned long long)v) - 1;
            v &= v - 1;
            int byt = wi*8 + (j >> 3);
            int p = byt / 96;
            int c = (byt - p*96)*8 + (j & 7);
            int dd = p / 18, px = p - dd*18;
            #pragma unroll
            for (int xi = 0; xi < 3; ++xi){
                int x = px - 2 + xi;
                if ((unsigned)x < 16u){
                    int tap = dd*3 + 2 - xi;
                    const short* wr_ = wcol + ((size_t)tap*C_ + c)*C_;
                    #pragma unroll
                    for (int q = 0; q < 3; ++q){
                        int co = tid + q*256;
                        accL[x*768 + co] += (int)wr_[co];
                    }
                }
            }
        }
    }
    __syncthreads();

    const float S = wmaxp[0] * (1.0f/32512.0f);
    #pragma unroll
    for (int q = 0; q < 3; ++q){
        int co = tid + q*256;
        float sc = sb[co], bi = sb[C_ + co];
        float* op = out + ((size_t)img*C_ + co)*NPIX + y*16;
        #pragma unroll
        for (int xg = 0; xg < 4; ++xg){
            f32x4 o4;
            #pragma unroll
            for (int rr = 0; rr < 4; ++rr){
                float accf = (float)accL[(xg*4+rr)*768 + co] * S;
                o4[rr] = __fadd_rn(__fmul_rn(accf, sc), bi);
            }
            *(f32x4*)(op + xg*4) = o4;
        }
    }
}

// ---------------------------------------------------------------------------
extern "C" void kernel_launch(void* const* d_in, const int* in_sizes, int n_in,
                              void* d_out, int out_size, void* d_ws, size_t ws_size,
                              hipStream_t stream)
{
    u8* ws = (u8*)d_ws;
    u8* wfrag = ws + OFF_WFRAG;
    short* wcol = (short*)(ws + OFF_WCOL);
    u8* xs_b = ws + OFF_BITS;
    u8* q_b  = ws + OFF_BITS + 1*BITSZ;
    u8* o_b  = ws + OFF_BITS + 4*BITSZ;
    float* sbt = (float*)(ws + OFF_SBT);
    float* wmaxb = (float*)(ws + OFF_WMAX);
    float* outp = (float*)d_out;

    hipMemsetAsync(ws + OFF_BITS, 0, 5*BITSZ, stream);   // bit halos must be 0
    hipMemsetAsync(wmaxb, 0, 16, stream);

    bn_prep4<<<dim3(3,4),256,0,stream>>>(
        (const float*)d_in[2],  (const float*)d_in[3],  (const float*)d_in[4],  (const float*)d_in[5],
        (const float*)d_in[7],  (const float*)d_in[8],  (const float*)d_in[9],  (const float*)d_in[10],
        (const float*)d_in[12], (const float*)d_in[13], (const float*)d_in[14], (const float*)d_in[15],
        (const float*)d_in[17], (const float*)d_in[18], (const float*)d_in[19], (const float*)d_in[20],
        sbt);
    wmax4<<<dim3(256,4),256,0,stream>>>(
        (const float*)d_in[1], (const float*)d_in[6],
        (const float*)d_in[11], (const float*)d_in[16], wmaxb);
    wprep_stage<<<dim3(48,12,4),256,0,stream>>>(
        (const float*)d_in[1], (const float*)d_in[6],
        (const float*)d_in[11], (const float*)d_in[16], wmaxb, wfrag, wcol);
    head_bits<<<1536,256,0,stream>>>((const float*)d_in[0], xs_b);

    conv_lif<<<dim3(1024,3),256,0,stream>>>(xs_b, wfrag, sbt, wmaxb, q_b);

    attn_bits<<<dim3(16,8),512,0,stream>>>(q_b, q_b + BITSZ, q_b + 2*BITSZ, o_b);
    pconv_sparse<<<1024,256,0,stream>>>(o_b, wcol, sbt + 4608, wmaxb + 3, outp);
}